// Round 7
// baseline (2180.177 us; speedup 1.0000x reference)
//
#include <hip/hip_runtime.h>
#include <hip/hip_bf16.h>

// LCA layer on MI355X — rank-factored steps, 16x16x32 MFMA, vectorized epilogue.
//   b = x@W ; g[j] = sum_k W[k][j]^2
//   u1 = 0.1 b ; a1 = relu(u1 - 0.1)
//   per step: t = a@W^T ; s = t@W ; u' = 0.9u + 0.1b - 0.1s + 0.1*a*g ; a' = relu(u'-0.1)
//   out = a@W^T (fp32)
// GEMM core: BMx128 tile, wave = 64x64 via 4x4 mfma_16x16x32_bf16 (bank-optimal),
// OPERAND SWAP (lane's 4 acc regs = 4 consecutive output cols at one row -> 8B/16B
// vector epilogue), BK/32 LDS planes, global_load_lds width-16, Bt ([N][K]) layout.
// BM=256/BK=32 for the M=8192,K=1024 GEMMs: LDS 24KB -> 4 blocks/CU -> the whole
// 1024-block grid resident in ONE scheduling round (48KB/3-block config wasted ~33%
// in a part-filled second round). T/OUT (K=4096) keep BK=64.

typedef __bf16 bf16_t;
typedef __bf16 bf16x8 __attribute__((ext_vector_type(8)));
typedef __bf16 bf16x4 __attribute__((ext_vector_type(4)));
typedef float  f32x4  __attribute__((ext_vector_type(4)));

__device__ __forceinline__ void g2lds16(const void* g, void* l) {
    __builtin_amdgcn_global_load_lds(
        (const __attribute__((address_space(1))) void*)g,
        (__attribute__((address_space(3))) void*)l,
        16, 0, 0);
}

enum { MODE_B = 0, MODE_T = 1, MODE_STEP2 = 2, MODE_OUT = 3 };

// C[m][n] = sum_k A[m][k] * Bt[n][k]  (A:[M][K], Bt:[N][K], bf16, K%BK==0,
// grid covers M in BM-tiles, N in 128-tiles).
template<int MODE, int BM, int BK>
__global__ __launch_bounds__((BM == 256) ? 512 : 256)
void gemm_bt(const bf16_t* __restrict__ A, const bf16_t* __restrict__ Bt,
             int N, int K,
             float*  __restrict__ outF,   // MODE_OUT: final fp32 output
             bf16_t* __restrict__ outH,   // MODE_T: t ; MODE_B/STEP2: a
             bf16_t* __restrict__ bb,     // MODE_B: write b ; MODE_STEP2: read b
             bf16_t* __restrict__ u,      // MODE_B: write u ; MODE_STEP2: rmw u
             const float* __restrict__ g) // MODE_STEP2: diag(W^T W), [N]
{
    constexpr int NT  = (BM == 256) ? 512 : 256;  // threads per block
    constexpr int NP  = BK / 32;                   // BK=32 planes
    constexpr int RPI = NT / 4;                    // rows covered per g2lds issue

    __shared__ __attribute__((aligned(16))) bf16_t As[NP * BM * 32];
    __shared__ __attribute__((aligned(16))) bf16_t Bs[NP * 128 * 32];

    const int t  = threadIdx.x;
    const int l  = t & 63;
    const int w  = t >> 6;                 // 2x2 (4 waves) or 4x2 (8 waves)
    const int wm = (w >> 1) * 64;
    const int wn = (w & 1) * 64;

    const int rowA = blockIdx.y * BM;
    const int colB = blockIdx.x * 128;

    // staging: thread t covers row t/4 (+RPI per extra issue) at k-offset (t&3)*8
    const int srow = t >> 2;               // 0..RPI-1
    const int skc  = (t & 3) * 8;
    const bf16_t* gA = A  + (size_t)(rowA + srow) * K + skc;
    const bf16_t* gB = Bt + (size_t)(colB + srow) * K + skc;
    char* lA = (char*)As + t * 16;
    char* lB = (char*)Bs + t * 16;

    f32x4 acc[4][4];
#pragma unroll
    for (int i = 0; i < 4; ++i)
#pragma unroll
        for (int j = 0; j < 4; ++j)
#pragma unroll
            for (int r = 0; r < 4; ++r) acc[i][j][r] = 0.f;

    // fragment read: lane l -> index (l&15), k (l>>4)*8 .. +7 (16B contiguous)
    const int lrow = l & 15;
    const int lk   = (l >> 4) * 8;
    const bf16_t* pA = As + (wm + lrow) * 32 + lk;
    const bf16_t* pB = Bs + (wn + lrow) * 32 + lk;

    for (int k0 = 0; k0 < K; k0 += BK) {
#pragma unroll
        for (int p = 0; p < NP; ++p) {     // plane p covers k0+p*32 .. +31
            const int kp = k0 + p * 32;
#pragma unroll
            for (int q = 0; q < BM / RPI; ++q)
                g2lds16(gA + kp + (size_t)q * RPI * K,
                        lA + p * (BM * 64) + q * (RPI * 64));
#pragma unroll
            for (int q = 0; q < 128 / RPI; ++q)
                g2lds16(gB + kp + (size_t)q * RPI * K,
                        lB + p * 8192 + q * (RPI * 64));
        }
        __syncthreads();   // vmcnt(0) drained before barrier -> LDS ready

#pragma unroll
        for (int p = 0; p < NP; ++p) {
            const bf16_t* qA = pA + p * (BM * 32);
            const bf16_t* qB = pB + p * 4096;
            bf16x8 af[4], bfr[4];
#pragma unroll
            for (int i = 0; i < 4; ++i) af[i]  = *(const bf16x8*)(qA + i * 16 * 32);
#pragma unroll
            for (int j = 0; j < 4; ++j) bfr[j] = *(const bf16x8*)(qB + j * 16 * 32);
            // OPERAND SWAP: (b_frag, a_frag) -> lane holds
            // C[m = wm+i*16+(l&15)][n = wn+j*16+(l>>4)*4 + r], r = 0..3 contiguous.
#pragma unroll
            for (int i = 0; i < 4; ++i)
#pragma unroll
                for (int j = 0; j < 4; ++j)
                    acc[i][j] = __builtin_amdgcn_mfma_f32_16x16x32_bf16(
                        bfr[j], af[i], acc[i][j], 0, 0, 0);
        }
        __syncthreads();
    }

    // epilogue (swapped layout): m = rowA+wm+i*16+(l&15), n = colB+wn+j*16+(l>>4)*4+r
    const int m0 = rowA + wm + (l & 15);
    const int n0 = colB + wn + ((l >> 4) * 4);

    f32x4 gvv[4];
    if (MODE == MODE_STEP2) {
#pragma unroll
        for (int j = 0; j < 4; ++j) gvv[j] = *(const f32x4*)(g + n0 + j * 16);
    }

#pragma unroll
    for (int i = 0; i < 4; ++i) {
        const int m = m0 + i * 16;
#pragma unroll
        for (int j = 0; j < 4; ++j) {
            const size_t idx = (size_t)m * N + (n0 + j * 16);
            const f32x4 c = acc[i][j];
            if (MODE == MODE_T) {
                bf16x4 o;
#pragma unroll
                for (int r = 0; r < 4; ++r) o[r] = (bf16_t)c[r];
                *(bf16x4*)(outH + idx) = o;
            } else if (MODE == MODE_B) {
                bf16x4 ob, ou, oa;
#pragma unroll
                for (int r = 0; r < 4; ++r) {
                    const float un = 0.1f * c[r];       // u1 = 0.1 b (u0=0 => a0=0)
                    ob[r] = (bf16_t)c[r];
                    ou[r] = (bf16_t)un;
                    oa[r] = (bf16_t)fmaxf(un - 0.1f, 0.f);
                }
                *(bf16x4*)(bb   + idx) = ob;
                *(bf16x4*)(u    + idx) = ou;
                *(bf16x4*)(outH + idx) = oa;
            } else if (MODE == MODE_STEP2) {
                const bf16x4 uv = *(const bf16x4*)(u  + idx);
                const bf16x4 bv = *(const bf16x4*)(bb + idx);
                bf16x4 ou, oa;
#pragma unroll
                for (int r = 0; r < 4; ++r) {
                    const float uo = (float)uv[r];
                    const float ao = fmaxf(uo - 0.1f, 0.f);    // a_old from u_old
                    const float un = 0.9f * uo + 0.1f * (float)bv[r]
                                   - 0.1f * c[r] + 0.1f * ao * gvv[j][r];
                    ou[r] = (bf16_t)un;
                    oa[r] = (bf16_t)fmaxf(un - 0.1f, 0.f);     // a_next (no race)
                }
                *(bf16x4*)(u    + idx) = ou;
                *(bf16x4*)(outH + idx) = oa;
            } else { // MODE_OUT
                *(f32x4*)(outF + idx) = c;
            }
        }
    }
}

__global__ void cast_x_kernel(const float* __restrict__ x, bf16_t* __restrict__ xh, int n) {
    int i = blockIdx.x * 256 + threadIdx.x;
    if (i < n) xh[i] = (bf16_t)x[i];
}

// Wh = bf16(W) [1024][4096] ; WT = bf16(W^T) [4096][1024]
__global__ void prep_w_kernel(const float* __restrict__ W,
                              bf16_t* __restrict__ Wh, bf16_t* __restrict__ WT) {
    int i = blockIdx.x * 256 + threadIdx.x;
    if (i < 1024 * 4096) {
        int k = i >> 12;
        int n = i & 4095;
        bf16_t v = (bf16_t)W[i];
        Wh[i] = v;
        WT[(size_t)n * 1024 + k] = v;
    }
}

// g[j] = sum_k W[k][j]^2
__global__ void prep_g_kernel(const float* __restrict__ W, float* __restrict__ g) {
    int j = blockIdx.x * 256 + threadIdx.x;
    if (j < 4096) {
        float s = 0.f;
        for (int k = 0; k < 1024; ++k) {
            float v = W[(size_t)k * 4096 + j];
            s += v * v;
        }
        g[j] = s;
    }
}

extern "C" void kernel_launch(void* const* d_in, const int* in_sizes, int n_in,
                              void* d_out, int out_size, void* d_ws, size_t ws_size,
                              hipStream_t stream)
{
    const float* x = (const float*)d_in[0];   // [8192][1024]
    const float* W = (const float*)d_in[1];   // [1024][4096]

    // d_out doubles as scratch until the final GEMM writes it:
    //   [0,16MiB): xh (bf16 x) until b-GEMM, then t ; [16MiB,+16KiB): g
    bf16_t* xh = (bf16_t*)d_out;
    bf16_t* tt = (bf16_t*)d_out;
    float*  gd = (float*)((char*)d_out + 16777216);

    char* ws = (char*)d_ws;                   // 208 MiB total (proven footprint)
    bf16_t* a  = (bf16_t*)(ws);               //  64 MiB [8192][4096]
    bf16_t* bb = (bf16_t*)(ws + 67108864);    //  64 MiB [8192][4096]
    bf16_t* u  = (bf16_t*)(ws + 134217728);   //  64 MiB [8192][4096]
    bf16_t* Wh = (bf16_t*)(ws + 201326592);   //   8 MiB [1024][4096]
    bf16_t* WT = (bf16_t*)(ws + 209715200);   //   8 MiB [4096][1024]

    cast_x_kernel<<<8388608 / 256, 256, 0, stream>>>(x, xh, 8388608);
    prep_w_kernel<<<4194304 / 256, 256, 0, stream>>>(W, Wh, WT);
    prep_g_kernel<<<16, 256, 0, stream>>>(W, gd);

    // b = x@W ; u1 = 0.1b ; a1 = relu(u1-0.1).  BM=256/BK=32 (24KB LDS, 4 blk/CU)
    gemm_bt<MODE_B, 256, 32><<<dim3(32, 32), 512, 0, stream>>>(xh, WT, 4096, 1024,
                                                               nullptr, a, bb, u, nullptr);
    // 9 remaining steps: t = a@W^T (BM=128/BK=64) ; s = t@W fused (BM=256/BK=32)
    for (int s = 0; s < 9; ++s) {
        gemm_bt<MODE_T, 128, 64><<<dim3(8, 64), 256, 0, stream>>>(a, Wh, 1024, 4096,
                                                                  nullptr, tt, nullptr, nullptr, nullptr);
        gemm_bt<MODE_STEP2, 256, 32><<<dim3(32, 32), 512, 0, stream>>>(tt, WT, 4096, 1024,
                                                                       nullptr, a, bb, u, gd);
    }
    // out = a@W^T : A=a, Bt=Wh, N=1024, K=4096, fp32 into d_out
    gemm_bt<MODE_OUT, 128, 64><<<dim3(8, 64), 256, 0, stream>>>(a, Wh, 1024, 4096,
                                                                (float*)d_out, nullptr, nullptr, nullptr, nullptr);
}